// Round 6
// baseline (18244.920 us; speedup 1.0000x reference)
//
#include <hip/hip_runtime.h>

#define BDIM 128
#define TDIM 1024
#define HDIM 256
#define SLOT (BDIM*HDIM)
#define NWG_WORK 64               // 48 layer (3 x 16 j-slices) + 16 head
#define NWG_TOTAL 256             // + 192 ballast WGs (clock-floor probe)
#define RING 14                   // h-plane ring depth per layer

// ws byte offsets — weights/biases read DIRECTLY from d_in (no mirrors).
#define FLAGS_OFF 0u              // u32 flag per (group g<4, wg<16) at u32 idx (g*16+w)*8
#define HD_OFF    2048u           // bf16 h digit planes [(l*RING+slot)*2+dig][B*H]
                                  //   = 3*14*2*65536 = 5,505,024 B
#define XF_OFF    5507072u        // fp32 x features [B][T][6] = 3,145,728 B
#define DONEF_OFF 8652800u        // fp32 done [B][T] = 524,288 B
#define DONE_OFF  9177088u        // u32 completion word (own cache line)
#define WS_NEEDED 9177092u
#define NZERO_U32 1376768         // (2048 + 5505024)/4 — flags + hd planes

typedef __attribute__((ext_vector_type(8))) short bf16x8;
typedef __attribute__((ext_vector_type(4))) float f32x4;

static __device__ __forceinline__ unsigned short f2bf(float f) {
  union { float f; unsigned u; } v; v.f = f;
  unsigned r = v.u + 0x7fffu + ((v.u >> 16) & 1u);   // RNE
  return (unsigned short)(r >> 16);
}
static __device__ __forceinline__ float bf2f(unsigned short h) {
  union { unsigned u; float f; } v; v.u = ((unsigned)h) << 16;
  return v.f;
}
static __device__ __forceinline__ float sigm(float x) { return 1.f / (1.f + __expf(-x)); }
static __device__ __forceinline__ float tanha(float x) { return 1.f - 2.f / (1.f + __expf(2.f * x)); }

// data-plane coherence: relaxed agent atomics (LLC-routed)
static __device__ __forceinline__ unsigned long long ld_u64_coh(const void* p) {
  return __hip_atomic_load((const unsigned long long*)p, __ATOMIC_RELAXED, __HIP_MEMORY_SCOPE_AGENT);
}
static __device__ __forceinline__ void st_u32_coh(void* p, unsigned v) {
  __hip_atomic_store((unsigned*)p, v, __ATOMIC_RELAXED, __HIP_MEMORY_SCOPE_AGENT);
}
static __device__ __forceinline__ bf16x8 ld_frag_coh(const unsigned short* p) {
  union { bf16x8 v; unsigned long long q[2]; } u;
  u.q[0] = ld_u64_coh(p);
  u.q[1] = ld_u64_coh(p + 4);
  return u.v;
}

static __device__ __forceinline__ unsigned poll_flag(const unsigned* p) {
  return __hip_atomic_load(p, __ATOMIC_RELAXED, __HIP_MEMORY_SCOPE_AGENT);
}
static __device__ __forceinline__ void post_flag(unsigned* fl, int g, int w, int s1) {
  (void)__hip_atomic_exchange(fl + (g * 16 + w) * 8, (unsigned)s1,
                              __ATOMIC_RELAXED, __HIP_MEMORY_SCOPE_AGENT);
}

// WG-level dataflow wait: only wave 0 polls; waves 1-3 park at the barrier.
static __device__ __forceinline__ void wg_wait(unsigned* fl,
                                               int g0, int t0,
                                               int g1, int t1,
                                               int g2, int t2,
                                               int skipw) {
  if ((threadIdx.x >> 6) == 0) {
    const int lane = threadIdx.x & 63;
    const int sel = lane >> 4;
    const int w = lane & 15;
    int g = g0, tgt = t0;
    if (sel == 1) { g = g1; tgt = t1; }
    if (sel == 2) { g = g2; tgt = t2; }
    if (sel == 3) tgt = 0;
    if (sel == 0 && w == skipw) tgt = 0;
    const unsigned* p = fl + (g * 16 + w) * 8;
    const bool need = tgt > 0;
    for (;;) {
      int ok = 1;
      if (need) ok = ((int)poll_flag(p) >= tgt);
      if (__all(ok)) break;
      __builtin_amdgcn_s_sleep(8);
    }
  }
  __syncthreads();
  asm volatile("" ::: "memory");
}

__global__ void diag_kernel(float* out, float code) {
  if (threadIdx.x == 0 && blockIdx.x == 0) out[0] = code;
}

// ---------- prep: zero flags + h planes + DONE, build x-features, mirror done ----------
__global__ void prep_kernel(const float* __restrict__ rew, const float* __restrict__ done,
                            const float* __restrict__ gamma, const float* __restrict__ prob,
                            const float* __restrict__ y, const float* __restrict__ y1,
                            const float* __restrict__ w_e1, const float* __restrict__ b_e1,
                            const float* __restrict__ w_e2, const float* __restrict__ b_e2,
                            char* __restrict__ ws) {
  unsigned* zbase = (unsigned*)ws;
  float* donef = (float*)(ws + DONEF_OFF);
  float* xfeat = (float*)(ws + XF_OFF);

  __shared__ float we1[480], be1[16], we2[16];
  __shared__ float be2s, gam;
  for (int i = threadIdx.x; i < 480; i += blockDim.x) we1[i] = w_e1[i];
  if (threadIdx.x < 16) { be1[threadIdx.x] = b_e1[threadIdx.x]; we2[threadIdx.x] = w_e2[threadIdx.x]; }
  if (threadIdx.x == 0) { be2s = b_e2[0]; gam = gamma[0]; }
  __syncthreads();
  const int gid = blockIdx.x * blockDim.x + threadIdx.x;
  const int stride = gridDim.x * blockDim.x;

  for (int i = gid; i < NZERO_U32; i += stride) zbase[i] = 0u;
  if (gid == 0) *(unsigned*)(ws + DONE_OFF) = 0u;
  for (int i = gid; i < BDIM * TDIM; i += stride) donef[i] = done[i];

  for (int i = gid; i < BDIM * TDIM; i += stride) {   // i = b*T + t
    float yr[30], y1r[30];
    #pragma unroll
    for (int c = 0; c < 30; ++c) { yr[c] = y[(size_t)i * 30 + c]; y1r[c] = y1[(size_t)i * 30 + c]; }
    float a0 = 0.f, a1 = 0.f;
    #pragma unroll 4
    for (int jm = 0; jm < 16; ++jm) {
      float s0 = be1[jm], s1 = be1[jm];
      #pragma unroll
      for (int c = 0; c < 30; ++c) { float w = we1[jm * 30 + c]; s0 += yr[c] * w; s1 += y1r[c] * w; }
      a0 += fmaxf(s0, 0.f) * we2[jm];
      a1 += fmaxf(s1, 0.f) * we2[jm];
    }
    float* xr = xfeat + (size_t)i * 6;
    xr[0] = rew[i]; xr[1] = done[i]; xr[2] = gam;
    xr[3] = prob[i]; xr[4] = sigm(a0 + be2s); xr[5] = sigm(a1 + be2s);
  }
}

// ---------------- layer WG: dataflow-synchronized MFMA step loop ----------------
// groups: 0=L0, 1=L1, 2=L2, 3=head. flag value = completed steps (s+1).
template <bool L0T>
__device__ __forceinline__ void layer_body(int l, int js, char* __restrict__ ws,
                                           char* __restrict__ ldsx,
                                           const float* __restrict__ Wh,
                                           const float* __restrict__ Wx,
                                           const float* __restrict__ bi,
                                           const float* __restrict__ bh,
                                           const float* __restrict__ wi0) {
  unsigned short* hd = (unsigned short*)(ws + HD_OFF);
  unsigned* fl = (unsigned*)(ws + FLAGS_OFF);
  const float* donef = (const float*)(ws + DONEF_OFF);
  const float* xfeat = (const float*)(ws + XF_OFF);

  const int tid = threadIdx.x;
  const int wv = tid >> 6, lane = tid & 63, q = lane >> 4, jj = lane & 15;
  const int j = js * 16 + jj;

  const float bi_r = bi[j], bi_z = bi[256 + j], bi_n = bi[512 + j];
  const float bh_r = bh[j], bh_z = bh[256 + j], bh_n = bh[512 + j];

  // Wh (d_in fp32) -> VGPR digit frags
  bf16x8 Bh[3][2][8];
  #pragma unroll
  for (int g = 0; g < 3; ++g)
    #pragma unroll
    for (int it = 0; it < 8; ++it) {
      const float* src = Wh + (size_t)(g * 256 + j) * 256 + it * 32 + q * 8;
      #pragma unroll
      for (int e = 0; e < 8; ++e) {
        const float w = src[e];
        const unsigned short d1 = f2bf(w);
        const unsigned short d2 = f2bf(w - bf2f(d1));
        Bh[g][0][it][e] = (short)d1;
        Bh[g][1][it][e] = (short)d2;
      }
    }

  // Wx -> LDS digit frags (l>0)
  if (!L0T) {
    for (int idx = tid; idx < 12288; idx += 256) {
      const int row = idx >> 8, k = idx & 255;
      const int g = row >> 4, jr = row & 15;
      const float w = Wx[(size_t)(g * 256 + js * 16 + jr) * 256 + k];
      const unsigned short d1 = f2bf(w);
      const unsigned short d2 = f2bf(w - bf2f(d1));
      const int it = k >> 5, kk = k & 31;
      *(unsigned short*)(ldsx + ((g * 2 + 0) * 8 + it) * 1280 + jr * 80 + kk * 2) = d1;
      *(unsigned short*)(ldsx + ((g * 2 + 1) * 8 + it) * 1280 + jr * 80 + kk * 2) = d2;
    }
  }
  __syncthreads();

  float wx0[3][6];
  if (L0T) {
    #pragma unroll
    for (int g = 0; g < 3; ++g)
      #pragma unroll
      for (int c = 0; c < 6; ++c) wx0[g][c] = wi0[(g * 256 + j) * 6 + c];
  }

  float hc[8];                     // WG-private fp32 carry
  #pragma unroll
  for (int i = 0; i < 8; ++i) hc[i] = 0.f;

  const int mA0 = (wv * 2) * 16 + jj;
  const f32x4 z4 = {0.f, 0.f, 0.f, 0.f};

  for (int s = 0; s < 1024; ++s) {
    const int t = 1023 - s;
    const int pc = s % RING, pp = (s + RING - 1) % RING;

    // prefetch done factors before the wait
    float sFv[2][4];
    #pragma unroll
    for (int mt = 0; mt < 2; ++mt)
      #pragma unroll
      for (int i = 0; i < 4; ++i)
        sFv[mt][i] = 1.f - donef[((wv * 2 + mt) * 16 + q * 4 + i) * TDIM + t];

    // dataflow waits:
    //  own layer done s-1: flag[l] >= s (own js auto-true)
    //  producer fresh:     flag[l-1] >= s+1
    //  consumer backpressure (deep ring): flag[next] >= s-RING+1
    if (L0T)         wg_wait(fl, 0, s, 1, s - (RING - 1), 1, 0,              js);
    else if (l == 1) wg_wait(fl, 1, s, 0, s + 1,          2, s - (RING - 1), js);
    else             wg_wait(fl, 2, s, 1, s + 1,          3, s - (RING - 1), js);

    const unsigned short* hh1 = hd + (size_t)((l * RING + pp) * 2 + 0) * SLOT;
    const unsigned short* hh2 = hd + (size_t)((l * RING + pp) * 2 + 1) * SLOT;
    const unsigned short* hx1 = L0T ? (const unsigned short*)0 : hd + (size_t)(((l - 1) * RING + pc) * 2 + 0) * SLOT;
    const unsigned short* hx2 = L0T ? (const unsigned short*)0 : hd + (size_t)(((l - 1) * RING + pc) * 2 + 1) * SLOT;
    unsigned short* hdw1 = hd + (size_t)((l * RING + pc) * 2 + 0) * SLOT;
    unsigned short* hdw2 = hd + (size_t)((l * RING + pc) * 2 + 1) * SLOT;

    f32x4 Ch[2][3], Cx[2][3];
    #pragma unroll
    for (int mt = 0; mt < 2; ++mt)
      #pragma unroll
      for (int g = 0; g < 3; ++g) { Ch[mt][g] = z4; Cx[mt][g] = z4; }

    #pragma unroll
    for (int it = 0; it < 8; ++it) {
      const int koff = it * 32 + q * 8;
      bf16x8 a1[2], a2[2], x1[2], x2[2];
      #pragma unroll
      for (int mt = 0; mt < 2; ++mt) {
        const int mA = mA0 + mt * 16;
        a1[mt] = ld_frag_coh(hh1 + (size_t)mA * 256 + koff);
        a2[mt] = ld_frag_coh(hh2 + (size_t)mA * 256 + koff);
        if (!L0T) {
          x1[mt] = ld_frag_coh(hx1 + (size_t)mA * 256 + koff);
          x2[mt] = ld_frag_coh(hx2 + (size_t)mA * 256 + koff);
        }
      }
      #pragma unroll
      for (int g = 0; g < 3; ++g) {
        #pragma unroll
        for (int dig = 0; dig < 2; ++dig) {
          const bf16x8 wb = Bh[g][dig][it];
          #pragma unroll
          for (int mt = 0; mt < 2; ++mt) {
            Ch[mt][g] = __builtin_amdgcn_mfma_f32_16x16x32_bf16(a1[mt], wb, Ch[mt][g], 0, 0, 0);
            Ch[mt][g] = __builtin_amdgcn_mfma_f32_16x16x32_bf16(a2[mt], wb, Ch[mt][g], 0, 0, 0);
          }
          if (!L0T) {
            const bf16x8 xb = *(const bf16x8*)(ldsx + ((g * 2 + dig) * 8 + it) * 1280 + jj * 80 + q * 16);
            #pragma unroll
            for (int mt = 0; mt < 2; ++mt) {
              Cx[mt][g] = __builtin_amdgcn_mfma_f32_16x16x32_bf16(x1[mt], xb, Cx[mt][g], 0, 0, 0);
              Cx[mt][g] = __builtin_amdgcn_mfma_f32_16x16x32_bf16(x2[mt], xb, Cx[mt][g], 0, 0, 0);
            }
          }
        }
      }
    }

    // epilogue (verified; C/D layout row=q*4+i, col=jj)
    #pragma unroll
    for (int mt = 0; mt < 2; ++mt) {
      #pragma unroll
      for (int i = 0; i < 4; ++i) {
        const int mC = (wv * 2 + mt) * 16 + q * 4 + i;
        const float sF = sFv[mt][i];
        float gxr, gxz, gxn;
        if (L0T) {
          const float* xr = xfeat + ((size_t)mC * TDIM + t) * 6;
          gxr = 0.f; gxz = 0.f; gxn = 0.f;
          #pragma unroll
          for (int c = 0; c < 6; ++c) {
            const float xv = xr[c];
            gxr += xv * wx0[0][c]; gxz += xv * wx0[1][c]; gxn += xv * wx0[2][c];
          }
        } else {
          gxr = Cx[mt][0][i]; gxz = Cx[mt][1][i]; gxn = Cx[mt][2][i];
        }
        const float r = sigm(gxr + bi_r + sF * Ch[mt][0][i] + bh_r);
        const float z = sigm(gxz + bi_z + sF * Ch[mt][1][i] + bh_z);
        const float n = tanha(gxn + bi_n + r * (sF * Ch[mt][2][i] + bh_n));
        const float hp = hc[mt * 4 + i] * sF;
        const float hv = (1.f - z) * n + z * hp;
        hc[mt * 4 + i] = hv;
        // lane-pair pack: even jj stores d1-plane u32 pair, odd jj d2-plane
        const unsigned short d1 = f2bf(hv);
        const unsigned short d2 = f2bf(hv - bf2f(d1));
        const int o1 = __shfl_xor((int)d1, 1, 64);
        const int o2 = __shfl_xor((int)d2, 1, 64);
        const unsigned val = (jj & 1) ? ((unsigned)(o2 & 0xffff) | ((unsigned)d2 << 16))
                                      : ((unsigned)d1 | ((unsigned)(o1 & 0xffff) << 16));
        unsigned short* bp = ((jj & 1) ? hdw2 : hdw1) + (size_t)mC * 256 + (j & ~1);
        st_u32_coh(bp, val);
      }
    }

    // drain stores, WG barrier, flag post (RMW)
    asm volatile("s_waitcnt vmcnt(0)" ::: "memory");
    __syncthreads();
    if (tid == 0) post_flag(fl, l, js, s + 1);
  }
}

// ---------------- head WGs: digit-plane reconstruct via LDS, fp32 dot ----------------
__device__ __forceinline__ void head_body(int hw, char* __restrict__ ws, float* __restrict__ out,
                                          char* __restrict__ lds,
                                          const float* __restrict__ wfy,
                                          const float* __restrict__ bfy,
                                          const float* __restrict__ wfp,
                                          const float* __restrict__ bfp) {
  const unsigned short* hd = (const unsigned short*)(ws + HD_OFF);
  unsigned* fl = (unsigned*)(ws + FLAGS_OFF);
  float* hlds = (float*)lds;        // 8 rows x 256 f32 = 8KB

  const int tid = threadIdx.x;
  const int d = tid & 31;           // 0..29 yo, 30 pi, 31 idle
  const int bb = tid >> 5;          // 0..7
  const int b = hw * 8 + bb;
  const bool act = d < 31;
  const float* wrow = (d < 30) ? (wfy + d * 256) : wfp;
  const float biasv = (d < 30) ? bfy[d] : bfp[0];

  for (int s = 0; s < 1024; ++s) {
    const int t = 1023 - s;
    const int pc = s % RING;
    wg_wait(fl, 2, s + 1, 0, 0, 0, 0, -1);

    // stage 8 rows: reconstruct h = d1 + d2 into LDS (err ~2^-18 — negligible)
    {
      const size_t rowoff = (size_t)(hw * 8 + (tid >> 5)) * 256 + (tid & 31) * 8;
      const unsigned short* p1 = hd + (size_t)((2 * RING + pc) * 2 + 0) * SLOT + rowoff;
      const unsigned short* p2 = hd + (size_t)((2 * RING + pc) * 2 + 1) * SLOT + rowoff;
      unsigned long long q10 = ld_u64_coh(p1);
      unsigned long long q11 = ld_u64_coh(p1 + 4);
      unsigned long long q20 = ld_u64_coh(p2);
      unsigned long long q21 = ld_u64_coh(p2 + 4);
      float* dst = hlds + (tid >> 5) * 256 + (tid & 31) * 8;
      #pragma unroll
      for (int e = 0; e < 4; ++e) {
        dst[e]     = bf2f((unsigned short)(q10 >> (16 * e))) + bf2f((unsigned short)(q20 >> (16 * e)));
        dst[4 + e] = bf2f((unsigned short)(q11 >> (16 * e))) + bf2f((unsigned short)(q21 >> (16 * e)));
      }
    }
    __syncthreads();
    if (act) {
      const float* hr = hlds + bb * 256;
      float a0 = 0.f, a1 = 0.f;
      #pragma unroll 8
      for (int kk = 0; kk < 256; kk += 8) {
        const f32x4 h0 = *(const f32x4*)(hr + kk);
        const f32x4 h1 = *(const f32x4*)(hr + kk + 4);
        const f32x4 w0 = *(const f32x4*)(wrow + kk);
        const f32x4 w1 = *(const f32x4*)(wrow + kk + 4);
        a0 += h0[0]*w0[0] + h0[1]*w0[1] + h0[2]*w0[2] + h0[3]*w0[3];
        a1 += h1[0]*w1[0] + h1[1]*w1[1] + h1[2]*w1[2] + h1[3]*w1[3];
      }
      const float acc = a0 + a1;
      if (d < 30) out[BDIM * TDIM + ((size_t)b * TDIM + t) * 30 + d] = sigm(acc + biasv);
      else        out[(size_t)b * TDIM + t] = acc + biasv;
    }
    __syncthreads();   // all lanes done with hlds + slot before consume-signal
    if (tid == 0) post_flag(fl, 3, hw, s + 1);
  }

  // completion: head WG 0 signals ballast WGs to exit
  if (hw == 0 && tid == 0)
    __hip_atomic_store((unsigned*)(ws + DONE_OFF), 1u,
                       __ATOMIC_RELAXED, __HIP_MEMORY_SCOPE_AGENT);
}

// ---------------- ballast WGs: keep the DPM governor at high clocks ----------------
// Pure-VALU spin (8 independent FMA chains, ~100% issue) + a DONE poll every
// ~4k cycles on a dedicated cache line. Occupies the 192 otherwise-idle CUs.
__device__ __forceinline__ void ballast_body(char* __restrict__ ws) {
  const unsigned* dp = (const unsigned*)(ws + DONE_OFF);
  float a0 = 1.0f, a1 = 1.1f, a2 = 1.2f, a3 = 1.3f;
  float a4 = 1.4f, a5 = 1.5f, a6 = 1.6f, a7 = 1.7f;
  for (;;) {
    #pragma unroll 64
    for (int i = 0; i < 512; ++i) {
      a0 = fmaf(a0, 1.0000001f, 1e-9f);
      a1 = fmaf(a1, 1.0000001f, 1e-9f);
      a2 = fmaf(a2, 1.0000001f, 1e-9f);
      a3 = fmaf(a3, 1.0000001f, 1e-9f);
      a4 = fmaf(a4, 1.0000001f, 1e-9f);
      a5 = fmaf(a5, 1.0000001f, 1e-9f);
      a6 = fmaf(a6, 1.0000001f, 1e-9f);
      a7 = fmaf(a7, 1.0000001f, 1e-9f);
    }
    asm volatile("" :: "v"(a0), "v"(a1), "v"(a2), "v"(a3),
                       "v"(a4), "v"(a5), "v"(a6), "v"(a7));
    if (__hip_atomic_load(dp, __ATOMIC_RELAXED, __HIP_MEMORY_SCOPE_AGENT) != 0u) break;
  }
}

__global__ void __launch_bounds__(256, 1) gru_main(char* __restrict__ ws,
                                                   float* __restrict__ out,
                                                   const float* __restrict__ wi0,
                                                   const float* __restrict__ wh0,
                                                   const float* __restrict__ bi0,
                                                   const float* __restrict__ bh0,
                                                   const float* __restrict__ wi1,
                                                   const float* __restrict__ wh1,
                                                   const float* __restrict__ bi1,
                                                   const float* __restrict__ bh1,
                                                   const float* __restrict__ wi2,
                                                   const float* __restrict__ wh2,
                                                   const float* __restrict__ bi2,
                                                   const float* __restrict__ bh2,
                                                   const float* __restrict__ wfy,
                                                   const float* __restrict__ bfy,
                                                   const float* __restrict__ wfp,
                                                   const float* __restrict__ bfp) {
  __shared__ char ldsx[61440];
  const int bid = blockIdx.x;
  if (bid < 48) {
    const int l = bid >> 4;
    const int js = bid & 15;
    const float* Wh = (l == 0) ? wh0 : (l == 1) ? wh1 : wh2;
    const float* Wx = (l == 0) ? (const float*)0 : (l == 1) ? wi1 : wi2;
    const float* bi = (l == 0) ? bi0 : (l == 1) ? bi1 : bi2;
    const float* bh = (l == 0) ? bh0 : (l == 1) ? bh1 : bh2;
    if (l == 0) layer_body<true>(l, js, ws, ldsx, Wh, Wx, bi, bh, wi0);
    else        layer_body<false>(l, js, ws, ldsx, Wh, Wx, bi, bh, wi0);
  } else if (bid < 64) {
    head_body(bid - 48, ws, out, ldsx, wfy, bfy, wfp, bfp);
  } else {
    ballast_body(ws);
  }
}

extern "C" void kernel_launch(void* const* d_in, const int* in_sizes, int n_in,
                              void* d_out, int out_size, void* d_ws, size_t ws_size,
                              hipStream_t stream) {
  static const int EXP_SIZES[26] = {131072, 131072, 1, 131072, 3932160, 3932160,
                                    4608, 196608, 768, 768,
                                    196608, 196608, 768, 768,
                                    196608, 196608, 768, 768,
                                    7680, 30, 256, 1, 480, 16, 16, 1};
  float code = 0.f;
  if (n_in != 26) code = 900.f;
  if (code == 0.f) {
    for (int i = 0; i < 26; ++i)
      if (in_sizes[i] != EXP_SIZES[i]) { code = 100.f + 4.f * (float)i; break; }
  }
  if (code == 0.f && out_size != 4063232) code = 400.f;
  if (code == 0.f && ws_size < (size_t)WS_NEEDED) code = 300.f;
  if (code != 0.f) {
    diag_kernel<<<1, 64, 0, stream>>>((float*)d_out, code);
    return;
  }

  char* ws = (char*)d_ws;
  prep_kernel<<<512, 256, 0, stream>>>(
      (const float*)d_in[0], (const float*)d_in[1], (const float*)d_in[2],
      (const float*)d_in[3], (const float*)d_in[4], (const float*)d_in[5],
      (const float*)d_in[22], (const float*)d_in[23], (const float*)d_in[24], (const float*)d_in[25],
      ws);
  gru_main<<<NWG_TOTAL, 256, 0, stream>>>(
      ws, (float*)d_out,
      (const float*)d_in[6], (const float*)d_in[7], (const float*)d_in[8], (const float*)d_in[9],
      (const float*)d_in[10], (const float*)d_in[11], (const float*)d_in[12], (const float*)d_in[13],
      (const float*)d_in[14], (const float*)d_in[15], (const float*)d_in[16], (const float*)d_in[17],
      (const float*)d_in[18], (const float*)d_in[19], (const float*)d_in[20], (const float*)d_in[21]);
}

// Round 7
// 18032.191 us; speedup vs baseline: 1.0118x; 1.0118x over previous
//
#include <hip/hip_runtime.h>

#define BDIM 128
#define TDIM 1024
#define HDIM 256
#define SLOT (BDIM*HDIM)
#define NWG_TOTAL 64              // 48 layer (3 x 16 j-slices) + 16 head
#define RING 14                   // h-plane ring depth per layer

// ws byte offsets — weights/biases read DIRECTLY from d_in (no mirrors).
#define FLAGS_OFF 0u              // u32 flag per (group g<4, wg<16) at u32 idx (g*16+w)*8
#define HD_OFF    2048u           // bf16 h digit planes [(l*RING+slot)*2+dig][B*H]
                                  //   = 3*14*2*65536 = 5,505,024 B
#define XF_OFF    5507072u        // fp32 x features [B][T][6] = 3,145,728 B
#define DONEF_OFF 8652800u        // fp32 done [B][T] = 524,288 B
#define WS_NEEDED 9177088u
#define NZERO_U32 1376768         // (2048 + 5505024)/4 — flags + hd planes

// dynamic LDS: Wh frags [0,61440) + Wx frags [61440,122880)
#define LDSW_BYTES 61440
#define LDS_TOTAL  122880

typedef __attribute__((ext_vector_type(8))) short bf16x8;
typedef __attribute__((ext_vector_type(4))) float f32x4;

static __device__ __forceinline__ unsigned short f2bf(float f) {
  union { float f; unsigned u; } v; v.f = f;
  unsigned r = v.u + 0x7fffu + ((v.u >> 16) & 1u);   // RNE
  return (unsigned short)(r >> 16);
}
static __device__ __forceinline__ float bf2f(unsigned short h) {
  union { unsigned u; float f; } v; v.u = ((unsigned)h) << 16;
  return v.f;
}
static __device__ __forceinline__ float sigm(float x) { return 1.f / (1.f + __expf(-x)); }
static __device__ __forceinline__ float tanha(float x) { return 1.f - 2.f / (1.f + __expf(2.f * x)); }

// data-plane coherence: relaxed agent atomics (LLC-routed)
static __device__ __forceinline__ unsigned long long ld_u64_coh(const void* p) {
  return __hip_atomic_load((const unsigned long long*)p, __ATOMIC_RELAXED, __HIP_MEMORY_SCOPE_AGENT);
}
static __device__ __forceinline__ void st_u32_coh(void* p, unsigned v) {
  __hip_atomic_store((unsigned*)p, v, __ATOMIC_RELAXED, __HIP_MEMORY_SCOPE_AGENT);
}
static __device__ __forceinline__ bf16x8 ld_frag_coh(const unsigned short* p) {
  union { bf16x8 v; unsigned long long q[2]; } u;
  u.q[0] = ld_u64_coh(p);
  u.q[1] = ld_u64_coh(p + 4);
  return u.v;
}

// flags (R16-frozen): poll = relaxed agent load; post = RMW at the LLC.
static __device__ __forceinline__ unsigned poll_flag(const unsigned* p) {
  return __hip_atomic_load(p, __ATOMIC_RELAXED, __HIP_MEMORY_SCOPE_AGENT);
}
static __device__ __forceinline__ void post_flag(unsigned* fl, int g, int w, int s1) {
  (void)__hip_atomic_exchange(fl + (g * 16 + w) * 8, (unsigned)s1,
                              __ATOMIC_RELAXED, __HIP_MEMORY_SCOPE_AGENT);
}

// WG-level dataflow wait (R16-frozen): only wave 0 polls; others park at barrier.
static __device__ __forceinline__ void wg_wait(unsigned* fl,
                                               int g0, int t0,
                                               int g1, int t1,
                                               int g2, int t2,
                                               int skipw) {
  if ((threadIdx.x >> 6) == 0) {
    const int lane = threadIdx.x & 63;
    const int sel = lane >> 4;
    const int w = lane & 15;
    int g = g0, tgt = t0;
    if (sel == 1) { g = g1; tgt = t1; }
    if (sel == 2) { g = g2; tgt = t2; }
    if (sel == 3) tgt = 0;
    if (sel == 0 && w == skipw) tgt = 0;
    const unsigned* p = fl + (g * 16 + w) * 8;
    const bool need = tgt > 0;
    for (;;) {
      int ok = 1;
      if (need) ok = ((int)poll_flag(p) >= tgt);
      if (__all(ok)) break;
      __builtin_amdgcn_s_sleep(8);
    }
  }
  __syncthreads();
  asm volatile("" ::: "memory");
}

__global__ void diag_kernel(float* out, float code) {
  if (threadIdx.x == 0 && blockIdx.x == 0) out[0] = code;
}

// ---------- prep: zero flags + h planes, build x-features, mirror done ----------
__global__ void prep_kernel(const float* __restrict__ rew, const float* __restrict__ done,
                            const float* __restrict__ gamma, const float* __restrict__ prob,
                            const float* __restrict__ y, const float* __restrict__ y1,
                            const float* __restrict__ w_e1, const float* __restrict__ b_e1,
                            const float* __restrict__ w_e2, const float* __restrict__ b_e2,
                            char* __restrict__ ws) {
  unsigned* zbase = (unsigned*)ws;
  float* donef = (float*)(ws + DONEF_OFF);
  float* xfeat = (float*)(ws + XF_OFF);

  __shared__ float we1[480], be1[16], we2[16];
  __shared__ float be2s, gam;
  for (int i = threadIdx.x; i < 480; i += blockDim.x) we1[i] = w_e1[i];
  if (threadIdx.x < 16) { be1[threadIdx.x] = b_e1[threadIdx.x]; we2[threadIdx.x] = w_e2[threadIdx.x]; }
  if (threadIdx.x == 0) { be2s = b_e2[0]; gam = gamma[0]; }
  __syncthreads();
  const int gid = blockIdx.x * blockDim.x + threadIdx.x;
  const int stride = gridDim.x * blockDim.x;

  for (int i = gid; i < NZERO_U32; i += stride) zbase[i] = 0u;
  for (int i = gid; i < BDIM * TDIM; i += stride) donef[i] = done[i];

  for (int i = gid; i < BDIM * TDIM; i += stride) {   // i = b*T + t
    float yr[30], y1r[30];
    #pragma unroll
    for (int c = 0; c < 30; ++c) { yr[c] = y[(size_t)i * 30 + c]; y1r[c] = y1[(size_t)i * 30 + c]; }
    float a0 = 0.f, a1 = 0.f;
    #pragma unroll 4
    for (int jm = 0; jm < 16; ++jm) {
      float s0 = be1[jm], s1 = be1[jm];
      #pragma unroll
      for (int c = 0; c < 30; ++c) { float w = we1[jm * 30 + c]; s0 += yr[c] * w; s1 += y1r[c] * w; }
      a0 += fmaxf(s0, 0.f) * we2[jm];
      a1 += fmaxf(s1, 0.f) * we2[jm];
    }
    float* xr = xfeat + (size_t)i * 6;
    xr[0] = rew[i]; xr[1] = done[i]; xr[2] = gam;
    xr[3] = prob[i]; xr[4] = sigm(a0 + be2s); xr[5] = sigm(a1 + be2s);
  }
}

// ---------------- layer WG: ROLLED-LOOP MFMA step (I$-footprint experiment) ----------
// Protocol byte-identical to R16. Wh digit frags now live in LDS (same padded
// fragment layout as Wx), so the it-loop rolls (4 x unroll-2 parity with named
// A/B frag buffers, 1-deep prefetch). Executed body ~1.1k inst vs ~2.5k.
template <bool L0T>
__device__ __forceinline__ void layer_body(int l, int js, char* __restrict__ ws,
                                           char* __restrict__ ldsW,
                                           char* __restrict__ ldsX,
                                           const float* __restrict__ Wh,
                                           const float* __restrict__ Wx,
                                           const float* __restrict__ bi,
                                           const float* __restrict__ bh,
                                           const float* __restrict__ wi0) {
  unsigned short* hd = (unsigned short*)(ws + HD_OFF);
  unsigned* fl = (unsigned*)(ws + FLAGS_OFF);
  const float* donef = (const float*)(ws + DONEF_OFF);
  const float* xfeat = (const float*)(ws + XF_OFF);

  const int tid = threadIdx.x;
  const int wv = tid >> 6, lane = tid & 63, q = lane >> 4, jj = lane & 15;
  const int j = js * 16 + jj;

  const float bi_r = bi[j], bi_z = bi[256 + j], bi_n = bi[512 + j];
  const float bh_r = bh[j], bh_z = bh[256 + j], bh_n = bh[512 + j];

  // stage Wh digit frags -> LDS (same layout/values as the old VGPR Bh path)
  for (int idx = tid; idx < 12288; idx += 256) {
    const int row = idx >> 8, k = idx & 255;
    const int g = row >> 4, jr = row & 15;
    const float w = Wh[(size_t)(g * 256 + js * 16 + jr) * 256 + k];
    const unsigned short d1 = f2bf(w);
    const unsigned short d2 = f2bf(w - bf2f(d1));
    const int itc = k >> 5, kk = k & 31;
    *(unsigned short*)(ldsW + ((g * 2 + 0) * 8 + itc) * 1280 + jr * 80 + kk * 2) = d1;
    *(unsigned short*)(ldsW + ((g * 2 + 1) * 8 + itc) * 1280 + jr * 80 + kk * 2) = d2;
  }
  // stage Wx digit frags (l>0)
  if (!L0T) {
    for (int idx = tid; idx < 12288; idx += 256) {
      const int row = idx >> 8, k = idx & 255;
      const int g = row >> 4, jr = row & 15;
      const float w = Wx[(size_t)(g * 256 + js * 16 + jr) * 256 + k];
      const unsigned short d1 = f2bf(w);
      const unsigned short d2 = f2bf(w - bf2f(d1));
      const int itc = k >> 5, kk = k & 31;
      *(unsigned short*)(ldsX + ((g * 2 + 0) * 8 + itc) * 1280 + jr * 80 + kk * 2) = d1;
      *(unsigned short*)(ldsX + ((g * 2 + 1) * 8 + itc) * 1280 + jr * 80 + kk * 2) = d2;
    }
  }
  __syncthreads();

  float wx0[3][6];
  if (L0T) {
    #pragma unroll
    for (int g = 0; g < 3; ++g)
      #pragma unroll
      for (int c = 0; c < 6; ++c) wx0[g][c] = wi0[(g * 256 + j) * 6 + c];
  }

  float hc[8];                     // WG-private fp32 carry
  #pragma unroll
  for (int i = 0; i < 8; ++i) hc[i] = 0.f;

  const int mA0 = (wv * 2) * 16 + jj;
  const f32x4 z4 = {0.f, 0.f, 0.f, 0.f};

  for (int s = 0; s < 1024; ++s) {
    const int t = 1023 - s;
    const int pc = s % RING, pp = (s + RING - 1) % RING;

    // prefetch done factors before the wait
    float sFv[2][4];
    #pragma unroll
    for (int mt = 0; mt < 2; ++mt)
      #pragma unroll
      for (int i = 0; i < 4; ++i)
        sFv[mt][i] = 1.f - donef[((wv * 2 + mt) * 16 + q * 4 + i) * TDIM + t];

    // dataflow waits (R16-frozen)
    if (L0T)         wg_wait(fl, 0, s, 1, s - (RING - 1), 1, 0,              js);
    else if (l == 1) wg_wait(fl, 1, s, 0, s + 1,          2, s - (RING - 1), js);
    else             wg_wait(fl, 2, s, 1, s + 1,          3, s - (RING - 1), js);

    const unsigned short* hh1 = hd + (size_t)((l * RING + pp) * 2 + 0) * SLOT;
    const unsigned short* hh2 = hd + (size_t)((l * RING + pp) * 2 + 1) * SLOT;
    const unsigned short* hx1 = L0T ? (const unsigned short*)0 : hd + (size_t)(((l - 1) * RING + pc) * 2 + 0) * SLOT;
    const unsigned short* hx2 = L0T ? (const unsigned short*)0 : hd + (size_t)(((l - 1) * RING + pc) * 2 + 1) * SLOT;
    unsigned short* hdw1 = hd + (size_t)((l * RING + pc) * 2 + 0) * SLOT;
    unsigned short* hdw2 = hd + (size_t)((l * RING + pc) * 2 + 1) * SLOT;

    f32x4 Ch[2][3], Cx[2][3];
    #pragma unroll
    for (int mt = 0; mt < 2; ++mt)
      #pragma unroll
      for (int g = 0; g < 3; ++g) { Ch[mt][g] = z4; Cx[mt][g] = z4; }

    // named A/B frag buffers (static register indexing — rule #20)
    bf16x8 a1A[2], a2A[2], x1A[2], x2A[2];
    bf16x8 a1B[2], a2B[2], x1B[2], x2B[2];

    auto LOADF = [&](int itv, bf16x8 (&A1)[2], bf16x8 (&A2)[2],
                     bf16x8 (&X1)[2], bf16x8 (&X2)[2]) {
      const int koff = itv * 32 + q * 8;
      #pragma unroll
      for (int mt = 0; mt < 2; ++mt) {
        const size_t ro = (size_t)(mA0 + mt * 16) * 256 + koff;
        A1[mt] = ld_frag_coh(hh1 + ro);
        A2[mt] = ld_frag_coh(hh2 + ro);
        if constexpr (!L0T) {
          X1[mt] = ld_frag_coh(hx1 + ro);
          X2[mt] = ld_frag_coh(hx2 + ro);
        }
      }
    };
    auto COMP = [&](int itv, bf16x8 (&A1)[2], bf16x8 (&A2)[2],
                    bf16x8 (&X1)[2], bf16x8 (&X2)[2]) {
      const int cb = itv * 1280 + jj * 80 + q * 16;
      #pragma unroll
      for (int g = 0; g < 3; ++g) {
        #pragma unroll
        for (int dig = 0; dig < 2; ++dig) {
          const bf16x8 wb = *(const bf16x8*)(ldsW + ((g * 2 + dig) * 8) * 1280 + cb);
          #pragma unroll
          for (int mt = 0; mt < 2; ++mt) {
            Ch[mt][g] = __builtin_amdgcn_mfma_f32_16x16x32_bf16(A1[mt], wb, Ch[mt][g], 0, 0, 0);
            Ch[mt][g] = __builtin_amdgcn_mfma_f32_16x16x32_bf16(A2[mt], wb, Ch[mt][g], 0, 0, 0);
          }
          if constexpr (!L0T) {
            const bf16x8 xb = *(const bf16x8*)(ldsX + ((g * 2 + dig) * 8) * 1280 + cb);
            #pragma unroll
            for (int mt = 0; mt < 2; ++mt) {
              Cx[mt][g] = __builtin_amdgcn_mfma_f32_16x16x32_bf16(X1[mt], xb, Cx[mt][g], 0, 0, 0);
              Cx[mt][g] = __builtin_amdgcn_mfma_f32_16x16x32_bf16(X2[mt], xb, Cx[mt][g], 0, 0, 0);
            }
          }
        }
      }
    };

    LOADF(0, a1A, a2A, x1A, x2A);
    #pragma unroll 1
    for (int ith = 0; ith < 4; ++ith) {
      LOADF(2 * ith + 1, a1B, a2B, x1B, x2B);
      COMP(2 * ith, a1A, a2A, x1A, x2A);
      if (ith < 3) LOADF(2 * ith + 2, a1A, a2A, x1A, x2A);
      COMP(2 * ith + 1, a1B, a2B, x1B, x2B);
    }

    // epilogue (verified; C/D layout row=q*4+i, col=jj)
    #pragma unroll
    for (int mt = 0; mt < 2; ++mt) {
      #pragma unroll
      for (int i = 0; i < 4; ++i) {
        const int mC = (wv * 2 + mt) * 16 + q * 4 + i;
        const float sF = sFv[mt][i];
        float gxr, gxz, gxn;
        if (L0T) {
          const float* xr = xfeat + ((size_t)mC * TDIM + t) * 6;
          gxr = 0.f; gxz = 0.f; gxn = 0.f;
          #pragma unroll
          for (int c = 0; c < 6; ++c) {
            const float xv = xr[c];
            gxr += xv * wx0[0][c]; gxz += xv * wx0[1][c]; gxn += xv * wx0[2][c];
          }
        } else {
          gxr = Cx[mt][0][i]; gxz = Cx[mt][1][i]; gxn = Cx[mt][2][i];
        }
        const float r = sigm(gxr + bi_r + sF * Ch[mt][0][i] + bh_r);
        const float z = sigm(gxz + bi_z + sF * Ch[mt][1][i] + bh_z);
        const float n = tanha(gxn + bi_n + r * (sF * Ch[mt][2][i] + bh_n));
        const float hp = hc[mt * 4 + i] * sF;
        const float hv = (1.f - z) * n + z * hp;
        hc[mt * 4 + i] = hv;
        // lane-pair pack: even jj stores d1-plane u32 pair, odd jj d2-plane
        const unsigned short d1 = f2bf(hv);
        const unsigned short d2 = f2bf(hv - bf2f(d1));
        const int o1 = __shfl_xor((int)d1, 1, 64);
        const int o2 = __shfl_xor((int)d2, 1, 64);
        const unsigned val = (jj & 1) ? ((unsigned)(o2 & 0xffff) | ((unsigned)d2 << 16))
                                      : ((unsigned)d1 | ((unsigned)(o1 & 0xffff) << 16));
        unsigned short* bp = ((jj & 1) ? hdw2 : hdw1) + (size_t)mC * 256 + (j & ~1);
        st_u32_coh(bp, val);
      }
    }

    // drain stores, WG barrier, flag post (RMW)
    asm volatile("s_waitcnt vmcnt(0)" ::: "memory");
    __syncthreads();
    if (tid == 0) post_flag(fl, l, js, s + 1);
  }
}

// ---------------- head WGs: digit-plane reconstruct via LDS, fp32 dot ----------------
__device__ __forceinline__ void head_body(int hw, char* __restrict__ ws, float* __restrict__ out,
                                          char* __restrict__ lds,
                                          const float* __restrict__ wfy,
                                          const float* __restrict__ bfy,
                                          const float* __restrict__ wfp,
                                          const float* __restrict__ bfp) {
  const unsigned short* hd = (const unsigned short*)(ws + HD_OFF);
  unsigned* fl = (unsigned*)(ws + FLAGS_OFF);
  float* hlds = (float*)lds;        // 8 rows x 256 f32 = 8KB

  const int tid = threadIdx.x;
  const int d = tid & 31;           // 0..29 yo, 30 pi, 31 idle
  const int bb = tid >> 5;          // 0..7
  const int b = hw * 8 + bb;
  const bool act = d < 31;
  const float* wrow = (d < 30) ? (wfy + d * 256) : wfp;
  const float biasv = (d < 30) ? bfy[d] : bfp[0];

  for (int s = 0; s < 1024; ++s) {
    const int t = 1023 - s;
    const int pc = s % RING;
    wg_wait(fl, 2, s + 1, 0, 0, 0, 0, -1);

    // stage 8 rows: reconstruct h = d1 + d2 into LDS (err ~2^-18 — negligible)
    {
      const size_t rowoff = (size_t)(hw * 8 + (tid >> 5)) * 256 + (tid & 31) * 8;
      const unsigned short* p1 = hd + (size_t)((2 * RING + pc) * 2 + 0) * SLOT + rowoff;
      const unsigned short* p2 = hd + (size_t)((2 * RING + pc) * 2 + 1) * SLOT + rowoff;
      unsigned long long q10 = ld_u64_coh(p1);
      unsigned long long q11 = ld_u64_coh(p1 + 4);
      unsigned long long q20 = ld_u64_coh(p2);
      unsigned long long q21 = ld_u64_coh(p2 + 4);
      float* dst = hlds + (tid >> 5) * 256 + (tid & 31) * 8;
      #pragma unroll
      for (int e = 0; e < 4; ++e) {
        dst[e]     = bf2f((unsigned short)(q10 >> (16 * e))) + bf2f((unsigned short)(q20 >> (16 * e)));
        dst[4 + e] = bf2f((unsigned short)(q11 >> (16 * e))) + bf2f((unsigned short)(q21 >> (16 * e)));
      }
    }
    __syncthreads();
    if (act) {
      const float* hr = hlds + bb * 256;
      float a0 = 0.f, a1 = 0.f;
      #pragma unroll 8
      for (int kk = 0; kk < 256; kk += 8) {
        const f32x4 h0 = *(const f32x4*)(hr + kk);
        const f32x4 h1 = *(const f32x4*)(hr + kk + 4);
        const f32x4 w0 = *(const f32x4*)(wrow + kk);
        const f32x4 w1 = *(const f32x4*)(wrow + kk + 4);
        a0 += h0[0]*w0[0] + h0[1]*w0[1] + h0[2]*w0[2] + h0[3]*w0[3];
        a1 += h1[0]*w1[0] + h1[1]*w1[1] + h1[2]*w1[2] + h1[3]*w1[3];
      }
      const float acc = a0 + a1;
      if (d < 30) out[BDIM * TDIM + ((size_t)b * TDIM + t) * 30 + d] = sigm(acc + biasv);
      else        out[(size_t)b * TDIM + t] = acc + biasv;
    }
    __syncthreads();   // all lanes done with hlds + slot before consume-signal
    if (tid == 0) post_flag(fl, 3, hw, s + 1);
  }
}

__global__ void __launch_bounds__(256, 1) gru_main(char* __restrict__ ws,
                                                   float* __restrict__ out,
                                                   const float* __restrict__ wi0,
                                                   const float* __restrict__ wh0,
                                                   const float* __restrict__ bi0,
                                                   const float* __restrict__ bh0,
                                                   const float* __restrict__ wi1,
                                                   const float* __restrict__ wh1,
                                                   const float* __restrict__ bi1,
                                                   const float* __restrict__ bh1,
                                                   const float* __restrict__ wi2,
                                                   const float* __restrict__ wh2,
                                                   const float* __restrict__ bi2,
                                                   const float* __restrict__ bh2,
                                                   const float* __restrict__ wfy,
                                                   const float* __restrict__ bfy,
                                                   const float* __restrict__ wfp,
                                                   const float* __restrict__ bfp) {
  extern __shared__ char lds[];
  const int bid = blockIdx.x;
  if (bid < 48) {
    const int l = bid >> 4;
    const int js = bid & 15;
    const float* Wh = (l == 0) ? wh0 : (l == 1) ? wh1 : wh2;
    const float* Wx = (l == 0) ? (const float*)0 : (l == 1) ? wi1 : wi2;
    const float* bi = (l == 0) ? bi0 : (l == 1) ? bi1 : bi2;
    const float* bh = (l == 0) ? bh0 : (l == 1) ? bh1 : bh2;
    if (l == 0) layer_body<true>(l, js, ws, lds, lds + LDSW_BYTES, Wh, Wx, bi, bh, wi0);
    else        layer_body<false>(l, js, ws, lds, lds + LDSW_BYTES, Wh, Wx, bi, bh, wi0);
  } else {
    head_body(bid - 48, ws, out, lds, wfy, bfy, wfp, bfp);
  }
}

extern "C" void kernel_launch(void* const* d_in, const int* in_sizes, int n_in,
                              void* d_out, int out_size, void* d_ws, size_t ws_size,
                              hipStream_t stream) {
  static const int EXP_SIZES[26] = {131072, 131072, 1, 131072, 3932160, 3932160,
                                    4608, 196608, 768, 768,
                                    196608, 196608, 768, 768,
                                    196608, 196608, 768, 768,
                                    7680, 30, 256, 1, 480, 16, 16, 1};
  float code = 0.f;
  if (n_in != 26) code = 900.f;
  if (code == 0.f) {
    for (int i = 0; i < 26; ++i)
      if (in_sizes[i] != EXP_SIZES[i]) { code = 100.f + 4.f * (float)i; break; }
  }
  if (code == 0.f && out_size != 4063232) code = 400.f;
  if (code == 0.f && ws_size < (size_t)WS_NEEDED) code = 300.f;
  if (code != 0.f) {
    diag_kernel<<<1, 64, 0, stream>>>((float*)d_out, code);
    return;
  }

  // opt-in to >64KB dynamic LDS (once; host-side attribute, graph-capture safe)
  static int attr_done = 0;
  if (!attr_done) {
    attr_done = 1;
    (void)hipFuncSetAttribute((const void*)gru_main,
                              hipFuncAttributeMaxDynamicSharedMemorySize, 131072);
  }

  char* ws = (char*)d_ws;
  prep_kernel<<<512, 256, 0, stream>>>(
      (const float*)d_in[0], (const float*)d_in[1], (const float*)d_in[2],
      (const float*)d_in[3], (const float*)d_in[4], (const float*)d_in[5],
      (const float*)d_in[22], (const float*)d_in[23], (const float*)d_in[24], (const float*)d_in[25],
      ws);
  gru_main<<<NWG_TOTAL, 256, LDS_TOTAL, stream>>>(
      ws, (float*)d_out,
      (const float*)d_in[6], (const float*)d_in[7], (const float*)d_in[8], (const float*)d_in[9],
      (const float*)d_in[10], (const float*)d_in[11], (const float*)d_in[12], (const float*)d_in[13],
      (const float*)d_in[14], (const float*)d_in[15], (const float*)d_in[16], (const float*)d_in[17],
      (const float*)d_in[18], (const float*)d_in[19], (const float*)d_in[20], (const float*)d_in[21]);
}

// Round 8
// 12503.250 us; speedup vs baseline: 1.4592x; 1.4422x over previous
//
#include <hip/hip_runtime.h>

#define BDIM 128
#define TDIM 1024
#define HDIM 256
#define SLOT (BDIM*HDIM)
#define NWG_TOTAL 208             // 192 worker (3 layer x 4 rowgroup x 16 colslice) + 16 head
#define RING 14                   // h-plane ring depth per layer

// ws byte offsets. Flags grew to 16 groups x 16 x 32B = 8192 B.
#define FLAGS_OFF 0u              // u32 flag at idx (g*16+w)*8; g = l*4+rg (worker), 12+rg (head)
#define HD_OFF    8192u           // bf16 h digit planes [(l*RING+slot)*2+dig][B*H] = 5,505,024 B
#define XF_OFF    5513216u        // fp32 x features [B][T][6] = 3,145,728 B
#define DONEF_OFF 8658944u       // fp32 done [B][T] = 524,288 B
#define WS_NEEDED 9183232u        // <= proven 9,245,840
#define NZERO_U32 1378304         // (8192 + 5505024)/4

#define LDS_DYN 98304             // forces 1 WG/CU (160KB pool); worker uses 61440, head 8KB

typedef __attribute__((ext_vector_type(8))) short bf16x8;
typedef __attribute__((ext_vector_type(4))) float f32x4;

static __device__ __forceinline__ unsigned short f2bf(float f) {
  union { float f; unsigned u; } v; v.f = f;
  unsigned r = v.u + 0x7fffu + ((v.u >> 16) & 1u);   // RNE
  return (unsigned short)(r >> 16);
}
static __device__ __forceinline__ float bf2f(unsigned short h) {
  union { unsigned u; float f; } v; v.u = ((unsigned)h) << 16;
  return v.f;
}
static __device__ __forceinline__ float sigm(float x) { return 1.f / (1.f + __expf(-x)); }
static __device__ __forceinline__ float tanha(float x) { return 1.f - 2.f / (1.f + __expf(2.f * x)); }

// data-plane coherence: relaxed agent atomics (LLC-routed) — R12-proven
static __device__ __forceinline__ unsigned long long ld_u64_coh(const void* p) {
  return __hip_atomic_load((const unsigned long long*)p, __ATOMIC_RELAXED, __HIP_MEMORY_SCOPE_AGENT);
}
static __device__ __forceinline__ void st_u32_coh(void* p, unsigned v) {
  __hip_atomic_store((unsigned*)p, v, __ATOMIC_RELAXED, __HIP_MEMORY_SCOPE_AGENT);
}
static __device__ __forceinline__ bf16x8 ld_frag_coh(const unsigned short* p) {
  union { bf16x8 v; unsigned long long q[2]; } u;
  u.q[0] = ld_u64_coh(p);
  u.q[1] = ld_u64_coh(p + 4);
  return u.v;
}

static __device__ __forceinline__ unsigned poll_flag(const unsigned* p) {
  return __hip_atomic_load(p, __ATOMIC_RELAXED, __HIP_MEMORY_SCOPE_AGENT);
}
static __device__ __forceinline__ void post_flag(unsigned* fl, int g, int w, int s1) {
  (void)__hip_atomic_exchange(fl + (g * 16 + w) * 8, (unsigned)s1,
                              __ATOMIC_RELAXED, __HIP_MEMORY_SCOPE_AGENT);
}

// single-wave dataflow wait: lanes 0-15 group g0 (skip own w=skip0),
// lanes 16-31 g1, lanes 32-47 g2 (g2four: only 4 flags, lane&3), 48-63 idle.
static __device__ __forceinline__ void wave_wait2(unsigned* fl,
                                                  int g0, int t0, int skip0,
                                                  int g1, int t1,
                                                  int g2, int t2, bool g2four) {
  const int lane = threadIdx.x & 63;
  const int sel = lane >> 4;
  const int w = lane & 15;
  int g = g0, tgt = t0;
  if (sel == 1) { g = g1; tgt = t1; }
  if (sel == 2) { g = g2; tgt = t2; }
  if (sel == 3) tgt = 0;
  if (sel == 0 && w == skip0) tgt = 0;
  const int wi = (sel == 2 && g2four) ? (w & 3) : w;
  const unsigned* p = fl + (g * 16 + wi) * 8;
  const bool need = tgt > 0;
  for (;;) {
    int ok = 1;
    if (need) ok = ((int)poll_flag(p) >= tgt);
    if (__all(ok)) break;
    __builtin_amdgcn_s_sleep(8);
  }
  asm volatile("" ::: "memory");
}

__global__ void diag_kernel(float* out, float code) {
  if (threadIdx.x == 0 && blockIdx.x == 0) out[0] = code;
}

// ---------- prep: zero flags + h planes, build x-features, mirror done ----------
__global__ void prep_kernel(const float* __restrict__ rew, const float* __restrict__ done,
                            const float* __restrict__ gamma, const float* __restrict__ prob,
                            const float* __restrict__ y, const float* __restrict__ y1,
                            const float* __restrict__ w_e1, const float* __restrict__ b_e1,
                            const float* __restrict__ w_e2, const float* __restrict__ b_e2,
                            char* __restrict__ ws) {
  unsigned* zbase = (unsigned*)ws;
  float* donef = (float*)(ws + DONEF_OFF);
  float* xfeat = (float*)(ws + XF_OFF);

  __shared__ float we1[480], be1[16], we2[16];
  __shared__ float be2s, gam;
  for (int i = threadIdx.x; i < 480; i += blockDim.x) we1[i] = w_e1[i];
  if (threadIdx.x < 16) { be1[threadIdx.x] = b_e1[threadIdx.x]; we2[threadIdx.x] = w_e2[threadIdx.x]; }
  if (threadIdx.x == 0) { be2s = b_e2[0]; gam = gamma[0]; }
  __syncthreads();
  const int gid = blockIdx.x * blockDim.x + threadIdx.x;
  const int stride = gridDim.x * blockDim.x;

  for (int i = gid; i < NZERO_U32; i += stride) zbase[i] = 0u;
  for (int i = gid; i < BDIM * TDIM; i += stride) donef[i] = done[i];

  for (int i = gid; i < BDIM * TDIM; i += stride) {   // i = b*T + t
    float yr[30], y1r[30];
    #pragma unroll
    for (int c = 0; c < 30; ++c) { yr[c] = y[(size_t)i * 30 + c]; y1r[c] = y1[(size_t)i * 30 + c]; }
    float a0 = 0.f, a1 = 0.f;
    #pragma unroll 4
    for (int jm = 0; jm < 16; ++jm) {
      float s0 = be1[jm], s1 = be1[jm];
      #pragma unroll
      for (int c = 0; c < 30; ++c) { float w = we1[jm * 30 + c]; s0 += yr[c] * w; s1 += y1r[c] * w; }
      a0 += fmaxf(s0, 0.f) * we2[jm];
      a1 += fmaxf(s1, 0.f) * we2[jm];
    }
    float* xr = xfeat + (size_t)i * 6;
    xr[0] = rew[i]; xr[1] = done[i]; xr[2] = gam;
    xr[3] = prob[i]; xr[4] = sigm(a0 + be2s); xr[5] = sigm(a1 + be2s);
  }
}

// ---------------- worker WG: ONE WAVE = one (layer, rowgroup, colslice) ----------------
// Per-lane math byte-identical to the proven 4-wave kernel (wv -> rg).
// flag groups: worker g = l*4+rg (w = js), head g = 12+rg (w = hw&3).
template <bool L0T>
__device__ __forceinline__ void layer_body(int l, int rg, int js, char* __restrict__ ws,
                                           char* __restrict__ ldsx,
                                           const float* __restrict__ Wh,
                                           const float* __restrict__ Wx,
                                           const float* __restrict__ bi,
                                           const float* __restrict__ bh,
                                           const float* __restrict__ wi0) {
  unsigned short* hd = (unsigned short*)(ws + HD_OFF);
  unsigned* fl = (unsigned*)(ws + FLAGS_OFF);
  const float* donef = (const float*)(ws + DONEF_OFF);
  const float* xfeat = (const float*)(ws + XF_OFF);

  const int tid = threadIdx.x;
  const int lane = tid & 63, q = lane >> 4, jj = lane & 15;
  const int j = js * 16 + jj;

  const float bi_r = bi[j], bi_z = bi[256 + j], bi_n = bi[512 + j];
  const float bh_r = bh[j], bh_z = bh[256 + j], bh_n = bh[512 + j];

  // Wh (d_in fp32) -> VGPR digit frags (identical values/layout to proven path)
  bf16x8 Bh[3][2][8];
  #pragma unroll
  for (int g = 0; g < 3; ++g)
    #pragma unroll
    for (int it = 0; it < 8; ++it) {
      const float* src = Wh + (size_t)(g * 256 + j) * 256 + it * 32 + q * 8;
      #pragma unroll
      for (int e = 0; e < 8; ++e) {
        const float w = src[e];
        const unsigned short d1 = f2bf(w);
        const unsigned short d2 = f2bf(w - bf2f(d1));
        Bh[g][0][it][e] = (short)d1;
        Bh[g][1][it][e] = (short)d2;
      }
    }

  // Wx -> LDS digit frags (l>0); 64 threads stage the 61440B slice
  if (!L0T) {
    for (int idx = tid; idx < 12288; idx += 64) {
      const int row = idx >> 8, k = idx & 255;
      const int g = row >> 4, jr = row & 15;
      const float w = Wx[(size_t)(g * 256 + js * 16 + jr) * 256 + k];
      const unsigned short d1 = f2bf(w);
      const unsigned short d2 = f2bf(w - bf2f(d1));
      const int it = k >> 5, kk = k & 31;
      *(unsigned short*)(ldsx + ((g * 2 + 0) * 8 + it) * 1280 + jr * 80 + kk * 2) = d1;
      *(unsigned short*)(ldsx + ((g * 2 + 1) * 8 + it) * 1280 + jr * 80 + kk * 2) = d2;
    }
  }
  __syncthreads();

  float wx0[3][6];
  if (L0T) {
    #pragma unroll
    for (int g = 0; g < 3; ++g)
      #pragma unroll
      for (int c = 0; c < 6; ++c) wx0[g][c] = wi0[(g * 256 + j) * 6 + c];
  }

  float hc[8];                     // fp32 carry for this WG's 32 rows x 16 cols
  #pragma unroll
  for (int i = 0; i < 8; ++i) hc[i] = 0.f;

  const int mA0 = (rg * 2) * 16 + jj;
  const f32x4 z4 = {0.f, 0.f, 0.f, 0.f};

  for (int s = 0; s < 1024; ++s) {
    const int t = 1023 - s;
    const int pc = s % RING, pp = (s + RING - 1) % RING;

    // prefetch done factors before the wait
    float sFv[2][4];
    #pragma unroll
    for (int mt = 0; mt < 2; ++mt)
      #pragma unroll
      for (int i = 0; i < 4; ++i)
        sFv[mt][i] = 1.f - donef[((rg * 2 + mt) * 16 + q * 4 + i) * TDIM + t];

    // dataflow waits (per rowgroup-pipeline):
    //  own-layer siblings done s-1, upstream fresh (s+1), downstream backpressure
    if (L0T)         wave_wait2(fl, rg,     s, js, 4 + rg,  s - (RING - 1), 0, 0, false);
    else if (l == 1) wave_wait2(fl, 4 + rg, s, js, rg,      s + 1, 8 + rg,  s - (RING - 1), false);
    else             wave_wait2(fl, 8 + rg, s, js, 4 + rg,  s + 1, 12 + rg, s - (RING - 1), true);

    const unsigned short* hh1 = hd + (size_t)((l * RING + pp) * 2 + 0) * SLOT;
    const unsigned short* hh2 = hd + (size_t)((l * RING + pp) * 2 + 1) * SLOT;
    const unsigned short* hx1 = L0T ? (const unsigned short*)0 : hd + (size_t)(((l - 1) * RING + pc) * 2 + 0) * SLOT;
    const unsigned short* hx2 = L0T ? (const unsigned short*)0 : hd + (size_t)(((l - 1) * RING + pc) * 2 + 1) * SLOT;
    unsigned short* hdw1 = hd + (size_t)((l * RING + pc) * 2 + 0) * SLOT;
    unsigned short* hdw2 = hd + (size_t)((l * RING + pc) * 2 + 1) * SLOT;

    f32x4 Ch[2][3], Cx[2][3];
    #pragma unroll
    for (int mt = 0; mt < 2; ++mt)
      #pragma unroll
      for (int g = 0; g < 3; ++g) { Ch[mt][g] = z4; Cx[mt][g] = z4; }

    #pragma unroll
    for (int it = 0; it < 8; ++it) {
      const int koff = it * 32 + q * 8;
      bf16x8 a1[2], a2[2], x1[2], x2[2];
      #pragma unroll
      for (int mt = 0; mt < 2; ++mt) {
        const int mA = mA0 + mt * 16;
        a1[mt] = ld_frag_coh(hh1 + (size_t)mA * 256 + koff);
        a2[mt] = ld_frag_coh(hh2 + (size_t)mA * 256 + koff);
        if (!L0T) {
          x1[mt] = ld_frag_coh(hx1 + (size_t)mA * 256 + koff);
          x2[mt] = ld_frag_coh(hx2 + (size_t)mA * 256 + koff);
        }
      }
      #pragma unroll
      for (int g = 0; g < 3; ++g) {
        #pragma unroll
        for (int dig = 0; dig < 2; ++dig) {
          const bf16x8 wb = Bh[g][dig][it];
          #pragma unroll
          for (int mt = 0; mt < 2; ++mt) {
            Ch[mt][g] = __builtin_amdgcn_mfma_f32_16x16x32_bf16(a1[mt], wb, Ch[mt][g], 0, 0, 0);
            Ch[mt][g] = __builtin_amdgcn_mfma_f32_16x16x32_bf16(a2[mt], wb, Ch[mt][g], 0, 0, 0);
          }
          if (!L0T) {
            const bf16x8 xb = *(const bf16x8*)(ldsx + ((g * 2 + dig) * 8 + it) * 1280 + jj * 80 + q * 16);
            #pragma unroll
            for (int mt = 0; mt < 2; ++mt) {
              Cx[mt][g] = __builtin_amdgcn_mfma_f32_16x16x32_bf16(x1[mt], xb, Cx[mt][g], 0, 0, 0);
              Cx[mt][g] = __builtin_amdgcn_mfma_f32_16x16x32_bf16(x2[mt], xb, Cx[mt][g], 0, 0, 0);
            }
          }
        }
      }
    }

    // epilogue (verified; C/D layout row=q*4+i, col=jj)
    #pragma unroll
    for (int mt = 0; mt < 2; ++mt) {
      #pragma unroll
      for (int i = 0; i < 4; ++i) {
        const int mC = (rg * 2 + mt) * 16 + q * 4 + i;
        const float sF = sFv[mt][i];
        float gxr, gxz, gxn;
        if (L0T) {
          const float* xr = xfeat + ((size_t)mC * TDIM + t) * 6;
          gxr = 0.f; gxz = 0.f; gxn = 0.f;
          #pragma unroll
          for (int c = 0; c < 6; ++c) {
            const float xv = xr[c];
            gxr += xv * wx0[0][c]; gxz += xv * wx0[1][c]; gxn += xv * wx0[2][c];
          }
        } else {
          gxr = Cx[mt][0][i]; gxz = Cx[mt][1][i]; gxn = Cx[mt][2][i];
        }
        const float r = sigm(gxr + bi_r + sF * Ch[mt][0][i] + bh_r);
        const float z = sigm(gxz + bi_z + sF * Ch[mt][1][i] + bh_z);
        const float n = tanha(gxn + bi_n + r * (sF * Ch[mt][2][i] + bh_n));
        const float hp = hc[mt * 4 + i] * sF;
        const float hv = (1.f - z) * n + z * hp;
        hc[mt * 4 + i] = hv;
        // lane-pair pack: even jj stores d1-plane u32 pair, odd jj d2-plane
        const unsigned short d1 = f2bf(hv);
        const unsigned short d2 = f2bf(hv - bf2f(d1));
        const int o1 = __shfl_xor((int)d1, 1, 64);
        const int o2 = __shfl_xor((int)d2, 1, 64);
        const unsigned val = (jj & 1) ? ((unsigned)(o2 & 0xffff) | ((unsigned)d2 << 16))
                                      : ((unsigned)d1 | ((unsigned)(o1 & 0xffff) << 16));
        unsigned short* bp = ((jj & 1) ? hdw2 : hdw1) + (size_t)mC * 256 + (j & ~1);
        st_u32_coh(bp, val);
      }
    }

    // drain stores, then flag post (RMW)
    asm volatile("s_waitcnt vmcnt(0)" ::: "memory");
    __syncthreads();
    if (tid == 0) post_flag(fl, l * 4 + rg, js, s + 1);
  }
}

// ---------------- head WG (64 threads, 8 batch rows) ----------------
// Same per-output math/order as the proven 256-thread head via tid_eff loop.
__device__ __forceinline__ void head_body(int hw, char* __restrict__ ws, float* __restrict__ out,
                                          char* __restrict__ lds,
                                          const float* __restrict__ wfy,
                                          const float* __restrict__ bfy,
                                          const float* __restrict__ wfp,
                                          const float* __restrict__ bfp) {
  const unsigned short* hd = (const unsigned short*)(ws + HD_OFF);
  unsigned* fl = (unsigned*)(ws + FLAGS_OFF);
  float* hlds = (float*)lds;        // 8 rows x 256 f32 = 8KB

  const int tid = threadIdx.x;
  const int rg = hw >> 2;

  for (int s = 0; s < 1024; ++s) {
    const int t = 1023 - s;
    const int pc = s % RING;
    wave_wait2(fl, 8 + rg, s + 1, -1, 0, 0, 0, 0, false);

    // stage 8 rows: reconstruct h = d1 + d2 into LDS (4 x 64-lane passes)
    #pragma unroll
    for (int sub = 0; sub < 4; ++sub) {
      const int te = tid + 64 * sub;
      const size_t rowoff = (size_t)(hw * 8 + (te >> 5)) * 256 + (te & 31) * 8;
      const unsigned short* p1 = hd + (size_t)((2 * RING + pc) * 2 + 0) * SLOT + rowoff;
      const unsigned short* p2 = hd + (size_t)((2 * RING + pc) * 2 + 1) * SLOT + rowoff;
      unsigned long long q10 = ld_u64_coh(p1);
      unsigned long long q11 = ld_u64_coh(p1 + 4);
      unsigned long long q20 = ld_u64_coh(p2);
      unsigned long long q21 = ld_u64_coh(p2 + 4);
      float* dst = hlds + (te >> 5) * 256 + (te & 31) * 8;
      #pragma unroll
      for (int e = 0; e < 4; ++e) {
        dst[e]     = bf2f((unsigned short)(q10 >> (16 * e))) + bf2f((unsigned short)(q20 >> (16 * e)));
        dst[4 + e] = bf2f((unsigned short)(q11 >> (16 * e))) + bf2f((unsigned short)(q21 >> (16 * e)));
      }
    }
    __syncthreads();
    #pragma unroll
    for (int sub = 0; sub < 4; ++sub) {
      const int te = tid + 64 * sub;
      const int d = te & 31;
      const int bb = te >> 5;
      const int b = hw * 8 + bb;
      if (d < 31) {
        const float* wrow = (d < 30) ? (wfy + d * 256) : wfp;
        const float biasv = (d < 30) ? bfy[d] : bfp[0];
        const float* hr = hlds + bb * 256;
        float a0 = 0.f, a1 = 0.f;
        #pragma unroll 8
        for (int kk = 0; kk < 256; kk += 8) {
          const f32x4 h0 = *(const f32x4*)(hr + kk);
          const f32x4 h1 = *(const f32x4*)(hr + kk + 4);
          const f32x4 w0 = *(const f32x4*)(wrow + kk);
          const f32x4 w1 = *(const f32x4*)(wrow + kk + 4);
          a0 += h0[0]*w0[0] + h0[1]*w0[1] + h0[2]*w0[2] + h0[3]*w0[3];
          a1 += h1[0]*w1[0] + h1[1]*w1[1] + h1[2]*w1[2] + h1[3]*w1[3];
        }
        const float acc = a0 + a1;
        if (d < 30) out[BDIM * TDIM + ((size_t)b * TDIM + t) * 30 + d] = sigm(acc + biasv);
        else        out[(size_t)b * TDIM + t] = acc + biasv;
      }
    }
    __syncthreads();
    if (tid == 0) post_flag(fl, 12 + rg, hw & 3, s + 1);
  }
}

__global__ void __launch_bounds__(64, 1) gru_main(char* __restrict__ ws,
                                                  float* __restrict__ out,
                                                  const float* __restrict__ wi0,
                                                  const float* __restrict__ wh0,
                                                  const float* __restrict__ bi0,
                                                  const float* __restrict__ bh0,
                                                  const float* __restrict__ wi1,
                                                  const float* __restrict__ wh1,
                                                  const float* __restrict__ bi1,
                                                  const float* __restrict__ bh1,
                                                  const float* __restrict__ wi2,
                                                  const float* __restrict__ wh2,
                                                  const float* __restrict__ bi2,
                                                  const float* __restrict__ bh2,
                                                  const float* __restrict__ wfy,
                                                  const float* __restrict__ bfy,
                                                  const float* __restrict__ wfp,
                                                  const float* __restrict__ bfp) {
  extern __shared__ char lds[];
  const int bid = blockIdx.x;
  if (bid < 192) {
    const int l = bid >> 6;
    const int rg = (bid >> 4) & 3;
    const int js = bid & 15;
    const float* Wh = (l == 0) ? wh0 : (l == 1) ? wh1 : wh2;
    const float* Wx = (l == 0) ? (const float*)0 : (l == 1) ? wi1 : wi2;
    const float* bi = (l == 0) ? bi0 : (l == 1) ? bi1 : bi2;
    const float* bh = (l == 0) ? bh0 : (l == 1) ? bh1 : bh2;
    if (l == 0) layer_body<true>(l, rg, js, ws, lds, Wh, Wx, bi, bh, wi0);
    else        layer_body<false>(l, rg, js, ws, lds, Wh, Wx, bi, bh, wi0);
  } else {
    head_body(bid - 192, ws, out, lds, wfy, bfy, wfp, bfp);
  }
}

extern "C" void kernel_launch(void* const* d_in, const int* in_sizes, int n_in,
                              void* d_out, int out_size, void* d_ws, size_t ws_size,
                              hipStream_t stream) {
  static const int EXP_SIZES[26] = {131072, 131072, 1, 131072, 3932160, 3932160,
                                    4608, 196608, 768, 768,
                                    196608, 196608, 768, 768,
                                    196608, 196608, 768, 768,
                                    7680, 30, 256, 1, 480, 16, 16, 1};
  float code = 0.f;
  if (n_in != 26) code = 900.f;
  if (code == 0.f) {
    for (int i = 0; i < 26; ++i)
      if (in_sizes[i] != EXP_SIZES[i]) { code = 100.f + 4.f * (float)i; break; }
  }
  if (code == 0.f && out_size != 4063232) code = 400.f;
  if (code == 0.f && ws_size < (size_t)WS_NEEDED) code = 300.f;
  if (code != 0.f) {
    diag_kernel<<<1, 64, 0, stream>>>((float*)d_out, code);
    return;
  }

  // opt-in to >64KB dynamic LDS (host-side attribute; proven in R18)
  static int attr_done = 0;
  if (!attr_done) {
    attr_done = 1;
    (void)hipFuncSetAttribute((const void*)gru_main,
                              hipFuncAttributeMaxDynamicSharedMemorySize, LDS_DYN);
  }

  char* ws = (char*)d_ws;
  prep_kernel<<<512, 256, 0, stream>>>(
      (const float*)d_in[0], (const float*)d_in[1], (const float*)d_in[2],
      (const float*)d_in[3], (const float*)d_in[4], (const float*)d_in[5],
      (const float*)d_in[22], (const float*)d_in[23], (const float*)d_in[24], (const float*)d_in[25],
      ws);
  gru_main<<<NWG_TOTAL, 64, LDS_DYN, stream>>>(
      ws, (float*)d_out,
      (const float*)d_in[6], (const float*)d_in[7], (const float*)d_in[8], (const float*)d_in[9],
      (const float*)d_in[10], (const float*)d_in[11], (const float*)d_in[12], (const float*)d_in[13],
      (const float*)d_in[14], (const float*)d_in[15], (const float*)d_in[16], (const float*)d_in[17],
      (const float*)d_in[18], (const float*)d_in[19], (const float*)d_in[20], (const float*)d_in[21]);
}

// Round 9
// 8733.295 us; speedup vs baseline: 2.0891x; 1.4317x over previous
//
#include <hip/hip_runtime.h>

#define BDIM 128
#define TDIM 1024
#define HDIM 256
#define SLOT (BDIM*HDIM)
#define NWG_TOTAL 208             // 192 worker (3 layer x 4 rowgroup x 16 colslice) + 16 head
#define RING 14                   // h-plane ring depth per layer

// ws byte offsets. Flags: 16 groups x 16 x 32B = 8192 B.
#define FLAGS_OFF 0u              // u32 flag at idx (g*16+w)*8; g = l*4+rg (worker), 12+rg (head)
#define HD_OFF    8192u           // bf16 h digit planes [(l*RING+slot)*2+dig][B*H] = 5,505,024 B
#define XF_OFF    5513216u        // fp32 x features [B][T][6] = 3,145,728 B
#define DONEF_OFF 8658944u        // fp32 done [B][T] = 524,288 B
#define WS_NEEDED 9183232u        // <= proven 9,245,840
#define NZERO_U32 1378304         // (8192 + 5505024)/4

#define LDS_DYN 98304             // forces 1 WG/CU; worker uses 61440, head 8KB

typedef __attribute__((ext_vector_type(8))) short bf16x8;
typedef __attribute__((ext_vector_type(4))) float f32x4;

static __device__ __forceinline__ unsigned short f2bf(float f) {
  union { float f; unsigned u; } v; v.f = f;
  unsigned r = v.u + 0x7fffu + ((v.u >> 16) & 1u);   // RNE
  return (unsigned short)(r >> 16);
}
static __device__ __forceinline__ float bf2f(unsigned short h) {
  union { unsigned u; float f; } v; v.u = ((unsigned)h) << 16;
  return v.f;
}
static __device__ __forceinline__ float sigm(float x) { return 1.f / (1.f + __expf(-x)); }
static __device__ __forceinline__ float tanha(float x) { return 1.f - 2.f / (1.f + __expf(2.f * x)); }

// data-plane coherence: relaxed agent atomics (LLC-routed) — R12-proven
static __device__ __forceinline__ unsigned long long ld_u64_coh(const void* p) {
  return __hip_atomic_load((const unsigned long long*)p, __ATOMIC_RELAXED, __HIP_MEMORY_SCOPE_AGENT);
}
static __device__ __forceinline__ void st_u32_coh(void* p, unsigned v) {
  __hip_atomic_store((unsigned*)p, v, __ATOMIC_RELAXED, __HIP_MEMORY_SCOPE_AGENT);
}
static __device__ __forceinline__ bf16x8 ld_frag_coh(const unsigned short* p) {
  union { bf16x8 v; unsigned long long q[2]; } u;
  u.q[0] = ld_u64_coh(p);
  u.q[1] = ld_u64_coh(p + 4);
  return u.v;
}

static __device__ __forceinline__ unsigned poll_flag(const unsigned* p) {
  return __hip_atomic_load(p, __ATOMIC_RELAXED, __HIP_MEMORY_SCOPE_AGENT);
}
static __device__ __forceinline__ void post_flag(unsigned* fl, int g, int w, int s1) {
  (void)__hip_atomic_exchange(fl + (g * 16 + w) * 8, (unsigned)s1,
                              __ATOMIC_RELAXED, __HIP_MEMORY_SCOPE_AGENT);
}

// per-wave dataflow wait: lanes 0-15 group g0 (skip own w=skip0),
// lanes 16-31 g1, lanes 32-47 g2 (g2four: only 4 flags, lane&3), 48-63 idle.
// Executed independently by every wave of the WG (identical conditions).
static __device__ __forceinline__ void wave_wait2(unsigned* fl,
                                                  int g0, int t0, int skip0,
                                                  int g1, int t1,
                                                  int g2, int t2, bool g2four) {
  const int lane = threadIdx.x & 63;
  const int sel = lane >> 4;
  const int w = lane & 15;
  int g = g0, tgt = t0;
  if (sel == 1) { g = g1; tgt = t1; }
  if (sel == 2) { g = g2; tgt = t2; }
  if (sel == 3) tgt = 0;
  if (sel == 0 && w == skip0) tgt = 0;
  const int wi = (sel == 2 && g2four) ? (w & 3) : w;
  const unsigned* p = fl + (g * 16 + wi) * 8;
  const bool need = tgt > 0;
  for (;;) {
    int ok = 1;
    if (need) ok = ((int)poll_flag(p) >= tgt);
    if (__all(ok)) break;
    __builtin_amdgcn_s_sleep(8);
  }
  asm volatile("" ::: "memory");
}

__global__ void diag_kernel(float* out, float code) {
  if (threadIdx.x == 0 && blockIdx.x == 0) out[0] = code;
}

// ---------- prep: zero flags + h planes, build x-features, mirror done ----------
__global__ void prep_kernel(const float* __restrict__ rew, const float* __restrict__ done,
                            const float* __restrict__ gamma, const float* __restrict__ prob,
                            const float* __restrict__ y, const float* __restrict__ y1,
                            const float* __restrict__ w_e1, const float* __restrict__ b_e1,
                            const float* __restrict__ w_e2, const float* __restrict__ b_e2,
                            char* __restrict__ ws) {
  unsigned* zbase = (unsigned*)ws;
  float* donef = (float*)(ws + DONEF_OFF);
  float* xfeat = (float*)(ws + XF_OFF);

  __shared__ float we1[480], be1[16], we2[16];
  __shared__ float be2s, gam;
  for (int i = threadIdx.x; i < 480; i += blockDim.x) we1[i] = w_e1[i];
  if (threadIdx.x < 16) { be1[threadIdx.x] = b_e1[threadIdx.x]; we2[threadIdx.x] = w_e2[threadIdx.x]; }
  if (threadIdx.x == 0) { be2s = b_e2[0]; gam = gamma[0]; }
  __syncthreads();
  const int gid = blockIdx.x * blockDim.x + threadIdx.x;
  const int stride = gridDim.x * blockDim.x;

  for (int i = gid; i < NZERO_U32; i += stride) zbase[i] = 0u;
  for (int i = gid; i < BDIM * TDIM; i += stride) donef[i] = done[i];

  for (int i = gid; i < BDIM * TDIM; i += stride) {   // i = b*T + t
    float yr[30], y1r[30];
    #pragma unroll
    for (int c = 0; c < 30; ++c) { yr[c] = y[(size_t)i * 30 + c]; y1r[c] = y1[(size_t)i * 30 + c]; }
    float a0 = 0.f, a1 = 0.f;
    #pragma unroll 4
    for (int jm = 0; jm < 16; ++jm) {
      float s0 = be1[jm], s1 = be1[jm];
      #pragma unroll
      for (int c = 0; c < 30; ++c) { float w = we1[jm * 30 + c]; s0 += yr[c] * w; s1 += y1r[c] * w; }
      a0 += fmaxf(s0, 0.f) * we2[jm];
      a1 += fmaxf(s1, 0.f) * we2[jm];
    }
    float* xr = xfeat + (size_t)i * 6;
    xr[0] = rew[i]; xr[1] = done[i]; xr[2] = gam;
    xr[3] = prob[i]; xr[4] = sigm(a0 + be2s); xr[5] = sigm(a1 + be2s);
  }
}

// ---------------- worker WG: TWO waves, wave wv owns rows (rg*2+wv)*16..+15 --------
// Per-lane math byte-identical to R19 (wave wv executes the old mt=wv iteration).
// flag groups: worker g = l*4+rg (w = js), head g = 12+rg (w = hw&3).
template <bool L0T>
__device__ __forceinline__ void layer_body(int l, int rg, int js, char* __restrict__ ws,
                                           char* __restrict__ ldsx,
                                           const float* __restrict__ Wh,
                                           const float* __restrict__ Wx,
                                           const float* __restrict__ bi,
                                           const float* __restrict__ bh,
                                           const float* __restrict__ wi0) {
  unsigned short* hd = (unsigned short*)(ws + HD_OFF);
  unsigned* fl = (unsigned*)(ws + FLAGS_OFF);
  const float* donef = (const float*)(ws + DONEF_OFF);
  const float* xfeat = (const float*)(ws + XF_OFF);

  const int tid = threadIdx.x;
  const int wv = tid >> 6, lane = tid & 63, q = lane >> 4, jj = lane & 15;
  const int j = js * 16 + jj;

  const float bi_r = bi[j], bi_z = bi[256 + j], bi_n = bi[512 + j];
  const float bh_r = bh[j], bh_z = bh[256 + j], bh_n = bh[512 + j];

  // Wh (d_in fp32) -> VGPR digit frags (identical values/layout; same in both waves)
  bf16x8 Bh[3][2][8];
  #pragma unroll
  for (int g = 0; g < 3; ++g)
    #pragma unroll
    for (int it = 0; it < 8; ++it) {
      const float* src = Wh + (size_t)(g * 256 + j) * 256 + it * 32 + q * 8;
      #pragma unroll
      for (int e = 0; e < 8; ++e) {
        const float w = src[e];
        const unsigned short d1 = f2bf(w);
        const unsigned short d2 = f2bf(w - bf2f(d1));
        Bh[g][0][it][e] = (short)d1;
        Bh[g][1][it][e] = (short)d2;
      }
    }

  // Wx -> LDS digit frags (l>0); 128 threads stage the 61440B slice
  if (!L0T) {
    for (int idx = tid; idx < 12288; idx += 128) {
      const int row = idx >> 8, k = idx & 255;
      const int g = row >> 4, jr = row & 15;
      const float w = Wx[(size_t)(g * 256 + js * 16 + jr) * 256 + k];
      const unsigned short d1 = f2bf(w);
      const unsigned short d2 = f2bf(w - bf2f(d1));
      const int it = k >> 5, kk = k & 31;
      *(unsigned short*)(ldsx + ((g * 2 + 0) * 8 + it) * 1280 + jr * 80 + kk * 2) = d1;
      *(unsigned short*)(ldsx + ((g * 2 + 1) * 8 + it) * 1280 + jr * 80 + kk * 2) = d2;
    }
  }
  __syncthreads();

  float wx0[3][6];
  if (L0T) {
    #pragma unroll
    for (int g = 0; g < 3; ++g)
      #pragma unroll
      for (int c = 0; c < 6; ++c) wx0[g][c] = wi0[(g * 256 + j) * 6 + c];
  }

  float hc[4];                     // fp32 carry: this wave's 16 rows x 16 cols
  #pragma unroll
  for (int i = 0; i < 4; ++i) hc[i] = 0.f;

  const int mA = (rg * 2 + wv) * 16 + jj;   // this wave's A-row base
  const f32x4 z4 = {0.f, 0.f, 0.f, 0.f};

  for (int s = 0; s < 1024; ++s) {
    const int t = 1023 - s;
    const int pc = s % RING, pp = (s + RING - 1) % RING;

    // prefetch done factors before the wait
    float sFv[4];
    #pragma unroll
    for (int i = 0; i < 4; ++i)
      sFv[i] = 1.f - donef[((rg * 2 + wv) * 16 + q * 4 + i) * TDIM + t];

    // dataflow waits (per rowgroup-pipeline) — both waves independently
    if (L0T)         wave_wait2(fl, rg,     s, js, 4 + rg,  s - (RING - 1), 0, 0, false);
    else if (l == 1) wave_wait2(fl, 4 + rg, s, js, rg,      s + 1, 8 + rg,  s - (RING - 1), false);
    else             wave_wait2(fl, 8 + rg, s, js, 4 + rg,  s + 1, 12 + rg, s - (RING - 1), true);

    const unsigned short* hh1 = hd + (size_t)((l * RING + pp) * 2 + 0) * SLOT;
    const unsigned short* hh2 = hd + (size_t)((l * RING + pp) * 2 + 1) * SLOT;
    const unsigned short* hx1 = L0T ? (const unsigned short*)0 : hd + (size_t)(((l - 1) * RING + pc) * 2 + 0) * SLOT;
    const unsigned short* hx2 = L0T ? (const unsigned short*)0 : hd + (size_t)(((l - 1) * RING + pc) * 2 + 1) * SLOT;
    unsigned short* hdw1 = hd + (size_t)((l * RING + pc) * 2 + 0) * SLOT;
    unsigned short* hdw2 = hd + (size_t)((l * RING + pc) * 2 + 1) * SLOT;

    f32x4 Ch[3], Cx[3];
    #pragma unroll
    for (int g = 0; g < 3; ++g) { Ch[g] = z4; Cx[g] = z4; }

    #pragma unroll
    for (int it = 0; it < 8; ++it) {
      const int koff = it * 32 + q * 8;
      const size_t ro = (size_t)mA * 256 + koff;
      bf16x8 a1 = ld_frag_coh(hh1 + ro);
      bf16x8 a2 = ld_frag_coh(hh2 + ro);
      bf16x8 x1{}, x2{};
      if (!L0T) {
        x1 = ld_frag_coh(hx1 + ro);
        x2 = ld_frag_coh(hx2 + ro);
      }
      #pragma unroll
      for (int g = 0; g < 3; ++g) {
        #pragma unroll
        for (int dig = 0; dig < 2; ++dig) {
          const bf16x8 wb = Bh[g][dig][it];
          Ch[g] = __builtin_amdgcn_mfma_f32_16x16x32_bf16(a1, wb, Ch[g], 0, 0, 0);
          Ch[g] = __builtin_amdgcn_mfma_f32_16x16x32_bf16(a2, wb, Ch[g], 0, 0, 0);
          if (!L0T) {
            const bf16x8 xb = *(const bf16x8*)(ldsx + ((g * 2 + dig) * 8 + it) * 1280 + jj * 80 + q * 16);
            Cx[g] = __builtin_amdgcn_mfma_f32_16x16x32_bf16(x1, xb, Cx[g], 0, 0, 0);
            Cx[g] = __builtin_amdgcn_mfma_f32_16x16x32_bf16(x2, xb, Cx[g], 0, 0, 0);
          }
        }
      }
    }

    // epilogue (verified; C/D layout row=q*4+i, col=jj)
    #pragma unroll
    for (int i = 0; i < 4; ++i) {
      const int mC = (rg * 2 + wv) * 16 + q * 4 + i;
      const float sF = sFv[i];
      float gxr, gxz, gxn;
      if (L0T) {
        const float* xr = xfeat + ((size_t)mC * TDIM + t) * 6;
        gxr = 0.f; gxz = 0.f; gxn = 0.f;
        #pragma unroll
        for (int c = 0; c < 6; ++c) {
          const float xv = xr[c];
          gxr += xv * wx0[0][c]; gxz += xv * wx0[1][c]; gxn += xv * wx0[2][c];
        }
      } else {
        gxr = Cx[0][i]; gxz = Cx[1][i]; gxn = Cx[2][i];
      }
      const float r = sigm(gxr + bi_r + sF * Ch[0][i] + bh_r);
      const float z = sigm(gxz + bi_z + sF * Ch[1][i] + bh_z);
      const float n = tanha(gxn + bi_n + r * (sF * Ch[2][i] + bh_n));
      const float hp = hc[i] * sF;
      const float hv = (1.f - z) * n + z * hp;
      hc[i] = hv;
      // lane-pair pack: even jj stores d1-plane u32 pair, odd jj d2-plane
      const unsigned short d1 = f2bf(hv);
      const unsigned short d2 = f2bf(hv - bf2f(d1));
      const int o1 = __shfl_xor((int)d1, 1, 64);
      const int o2 = __shfl_xor((int)d2, 1, 64);
      const unsigned val = (jj & 1) ? ((unsigned)(o2 & 0xffff) | ((unsigned)d2 << 16))
                                    : ((unsigned)d1 | ((unsigned)(o1 & 0xffff) << 16));
      unsigned short* bp = ((jj & 1) ? hdw2 : hdw1) + (size_t)mC * 256 + (j & ~1);
      st_u32_coh(bp, val);
    }

    // drain this wave's stores, join sibling wave, then flag post (RMW)
    asm volatile("s_waitcnt vmcnt(0)" ::: "memory");
    __syncthreads();
    if (tid == 0) post_flag(fl, l * 4 + rg, js, s + 1);
  }
}

// ---------------- head WG (128 threads, 8 batch rows) ----------------
__device__ __forceinline__ void head_body(int hw, char* __restrict__ ws, float* __restrict__ out,
                                          char* __restrict__ lds,
                                          const float* __restrict__ wfy,
                                          const float* __restrict__ bfy,
                                          const float* __restrict__ wfp,
                                          const float* __restrict__ bfp) {
  const unsigned short* hd = (const unsigned short*)(ws + HD_OFF);
  unsigned* fl = (unsigned*)(ws + FLAGS_OFF);
  float* hlds = (float*)lds;        // 8 rows x 256 f32 = 8KB

  const int tid = threadIdx.x;
  const int rg = hw >> 2;

  for (int s = 0; s < 1024; ++s) {
    const int t = 1023 - s;
    const int pc = s % RING;
    wave_wait2(fl, 8 + rg, s + 1, -1, 0, 0, 0, 0, false);

    // stage 8 rows: reconstruct h = d1 + d2 into LDS (2 x 128-lane passes)
    #pragma unroll
    for (int sub = 0; sub < 2; ++sub) {
      const int te = tid + 128 * sub;
      const size_t rowoff = (size_t)(hw * 8 + (te >> 5)) * 256 + (te & 31) * 8;
      const unsigned short* p1 = hd + (size_t)((2 * RING + pc) * 2 + 0) * SLOT + rowoff;
      const unsigned short* p2 = hd + (size_t)((2 * RING + pc) * 2 + 1) * SLOT + rowoff;
      unsigned long long q10 = ld_u64_coh(p1);
      unsigned long long q11 = ld_u64_coh(p1 + 4);
      unsigned long long q20 = ld_u64_coh(p2);
      unsigned long long q21 = ld_u64_coh(p2 + 4);
      float* dst = hlds + (te >> 5) * 256 + (te & 31) * 8;
      #pragma unroll
      for (int e = 0; e < 4; ++e) {
        dst[e]     = bf2f((unsigned short)(q10 >> (16 * e))) + bf2f((unsigned short)(q20 >> (16 * e)));
        dst[4 + e] = bf2f((unsigned short)(q11 >> (16 * e))) + bf2f((unsigned short)(q21 >> (16 * e)));
      }
    }
    __syncthreads();
    #pragma unroll
    for (int sub = 0; sub < 2; ++sub) {
      const int te = tid + 128 * sub;
      const int d = te & 31;
      const int bb = te >> 5;
      const int b = hw * 8 + bb;
      if (d < 31) {
        const float* wrow = (d < 30) ? (wfy + d * 256) : wfp;
        const float biasv = (d < 30) ? bfy[d] : bfp[0];
        const float* hr = hlds + bb * 256;
        float a0 = 0.f, a1 = 0.f;
        #pragma unroll 8
        for (int kk = 0; kk < 256; kk += 8) {
          const f32x4 h0 = *(const f32x4*)(hr + kk);
          const f32x4 h1 = *(const f32x4*)(hr + kk + 4);
          const f32x4 w0 = *(const f32x4*)(wrow + kk);
          const f32x4 w1 = *(const f32x4*)(wrow + kk + 4);
          a0 += h0[0]*w0[0] + h0[1]*w0[1] + h0[2]*w0[2] + h0[3]*w0[3];
          a1 += h1[0]*w1[0] + h1[1]*w1[1] + h1[2]*w1[2] + h1[3]*w1[3];
        }
        const float acc = a0 + a1;
        if (d < 30) out[BDIM * TDIM + ((size_t)b * TDIM + t) * 30 + d] = sigm(acc + biasv);
        else        out[(size_t)b * TDIM + t] = acc + biasv;
      }
    }
    __syncthreads();
    if (tid == 0) post_flag(fl, 12 + rg, hw & 3, s + 1);
  }
}

__global__ void __launch_bounds__(128, 1) gru_main(char* __restrict__ ws,
                                                   float* __restrict__ out,
                                                   const float* __restrict__ wi0,
                                                   const float* __restrict__ wh0,
                                                   const float* __restrict__ bi0,
                                                   const float* __restrict__ bh0,
                                                   const float* __restrict__ wi1,
                                                   const float* __restrict__ wh1,
                                                   const float* __restrict__ bi1,
                                                   const float* __restrict__ bh1,
                                                   const float* __restrict__ wi2,
                                                   const float* __restrict__ wh2,
                                                   const float* __restrict__ bi2,
                                                   const float* __restrict__ bh2,
                                                   const float* __restrict__ wfy,
                                                   const float* __restrict__ bfy,
                                                   const float* __restrict__ wfp,
                                                   const float* __restrict__ bfp) {
  extern __shared__ char lds[];
  const int bid = blockIdx.x;
  if (bid < 192) {
    const int l = bid >> 6;
    const int rg = (bid >> 4) & 3;
    const int js = bid & 15;
    const float* Wh = (l == 0) ? wh0 : (l == 1) ? wh1 : wh2;
    const float* Wx = (l == 0) ? (const float*)0 : (l == 1) ? wi1 : wi2;
    const float* bi = (l == 0) ? bi0 : (l == 1) ? bi1 : bi2;
    const float* bh = (l == 0) ? bh0 : (l == 1) ? bh1 : bh2;
    if (l == 0) layer_body<true>(l, rg, js, ws, lds, Wh, Wx, bi, bh, wi0);
    else        layer_body<false>(l, rg, js, ws, lds, Wh, Wx, bi, bh, wi0);
  } else {
    head_body(bid - 192, ws, out, lds, wfy, bfy, wfp, bfp);
  }
}

extern "C" void kernel_launch(void* const* d_in, const int* in_sizes, int n_in,
                              void* d_out, int out_size, void* d_ws, size_t ws_size,
                              hipStream_t stream) {
  static const int EXP_SIZES[26] = {131072, 131072, 1, 131072, 3932160, 3932160,
                                    4608, 196608, 768, 768,
                                    196608, 196608, 768, 768,
                                    196608, 196608, 768, 768,
                                    7680, 30, 256, 1, 480, 16, 16, 1};
  float code = 0.f;
  if (n_in != 26) code = 900.f;
  if (code == 0.f) {
    for (int i = 0; i < 26; ++i)
      if (in_sizes[i] != EXP_SIZES[i]) { code = 100.f + 4.f * (float)i; break; }
  }
  if (code == 0.f && out_size != 4063232) code = 400.f;
  if (code == 0.f && ws_size < (size_t)WS_NEEDED) code = 300.f;
  if (code != 0.f) {
    diag_kernel<<<1, 64, 0, stream>>>((float*)d_out, code);
    return;
  }

  // opt-in to >64KB dynamic LDS (host-side attribute; proven in R18/R19)
  static int attr_done = 0;
  if (!attr_done) {
    attr_done = 1;
    (void)hipFuncSetAttribute((const void*)gru_main,
                              hipFuncAttributeMaxDynamicSharedMemorySize, LDS_DYN);
  }

  char* ws = (char*)d_ws;
  prep_kernel<<<512, 256, 0, stream>>>(
      (const float*)d_in[0], (const float*)d_in[1], (const float*)d_in[2],
      (const float*)d_in[3], (const float*)d_in[4], (const float*)d_in[5],
      (const float*)d_in[22], (const float*)d_in[23], (const float*)d_in[24], (const float*)d_in[25],
      ws);
  gru_main<<<NWG_TOTAL, 128, LDS_DYN, stream>>>(
      ws, (float*)d_out,
      (const float*)d_in[6], (const float*)d_in[7], (const float*)d_in[8], (const float*)d_in[9],
      (const float*)d_in[10], (const float*)d_in[11], (const float*)d_in[12], (const float*)d_in[13],
      (const float*)d_in[14], (const float*)d_in[15], (const float*)d_in[16], (const float*)d_in[17],
      (const float*)d_in[18], (const float*)d_in[19], (const float*)d_in[20], (const float*)d_in[21]);
}